// Round 4
// baseline (249.258 us; speedup 1.0000x reference)
//
#include <hip/hip_runtime.h>
#include <math.h>

#define NB 2048
#define NF 42
#define NC 521

// BRUX_COMBOS flattened: 13 combos x 3 (class, lo, hi)
__constant__ int   d_ccls[39] = {
    500, 41,  0,
    369, 500, 0,
    412, 431, 470,
    127, 67,  103,
    399, 403, 412,
    410, 411, 398,
    412, 410, 398,
    435, 438, 449,
    374, 436, 435,
    372, 434, 469,
    500, 439, 50,
    399, 403, 410,
    410, 398, 435};
__constant__ float d_clo[39] = {
    0.1f, 0.05f, 0.0f,
    0.1f, 0.1f,  0.0f,
    0.05f,0.05f, 0.05f,
    0.1f, 0.1f,  0.1f,
    0.1f, 0.1f,  0.1f,
    0.1f, 0.1f,  0.1f,
    0.1f, 0.1f,  0.1f,
    0.1f, 0.1f,  0.1f,
    0.1f, 0.1f,  0.1f,
    0.1f, 0.1f,  0.1f,
    0.1f, 0.1f,  0.1f,
    0.1f, 0.1f,  0.1f,
    0.1f, 0.1f,  0.1f};
__constant__ float d_chi[39] = {
    0.8f, 0.5f, 1.0f,
    0.5f, 0.5f, 1.0f,
    0.4f, 0.4f, 0.4f,
    0.8f, 0.7f, 0.6f,
    0.9f, 0.8f, 0.7f,
    0.9f, 0.8f, 0.7f,
    0.8f, 0.7f, 0.6f,
    0.9f, 0.8f, 0.7f,
    0.9f, 0.8f, 0.7f,
    0.9f, 0.8f, 0.7f,
    0.8f, 0.7f, 0.6f,
    0.9f, 0.8f, 0.7f,
    0.9f, 0.8f, 0.7f};
// round(score*100)/100 in f32 is identity for these constants
__constant__ float d_btab[13] = {2.94f, 1.76f, 1.76f, 1.47f, 0.29f, 0.88f, 0.01f,
                                 0.29f, 0.29f, 0.01f, 0.29f, 0.01f, 0.01f};

__global__ __launch_bounds__(256, 8)
void sleep_cls_kernel(const float* __restrict__ score, float* __restrict__ out) {
    const int b    = blockIdx.x;
    const int tid  = threadIdx.x;
    const int wave = tid >> 6;
    const int lane = tid & 63;
    const float* base = score + (size_t)b * (NF * NC);

    __shared__ int   s_bfj[NF];
    __shared__ float s_bfs[NF];
    __shared__ int   s_cfj[NF];
    __shared__ float s_cfs[NF];

    // ---- stage 1: per-frame classification (wave w handles frames w, w+4, ...)
    for (int f = wave; f < NF; f += 4) {
        const float* row = base + f * NC;
        // pivot values for rank tests (same addr across lanes -> one fetch)
        const float v0  = row[0];
        const float v38 = row[38];
        const float v42 = row[42];

        // stream the row: 8 coalesced loads in flight + 9-lane tail
        float vv[8];
#pragma unroll
        for (int k = 0; k < 8; ++k) vv[k] = row[lane + (k << 6)];

        int cnt = 0;  // packed: rank0 | rank38<<10 | rank42<<20 (each <= 521 < 1024)
        {   // k = 0: j = lane in [0,64) -> tie-break (j < c) can apply
            const float v = vv[0];
            const int   j = lane;
            cnt += (int)(v > v0)
                 + ((int)((v > v38) || ((v == v38) && (j < 38))) << 10)
                 + ((int)((v > v42) || ((v == v42) && (j < 42))) << 20);
        }
#pragma unroll
        for (int k = 1; k < 8; ++k) {  // j >= 64 > 42: tie-break never applies
            const float v = vv[k];
            cnt += (int)(v > v0) + ((int)(v > v38) << 10) + ((int)(v > v42) << 20);
        }
        if (lane < 9) {  // tail: j = lane + 512 in [512, 521)
            const float v = row[lane + 512];
            cnt += (int)(v > v0) + ((int)(v > v38) << 10) + ((int)(v > v42) << 20);
        }
        // wave-sum of packed counters
#pragma unroll
        for (int s = 32; s > 0; s >>= 1) cnt += __shfl_xor(cnt, s);

        const int  c0  = cnt & 1023;
        const int  c38 = (cnt >> 10) & 1023;
        const int  c42 = (cnt >> 20) & 1023;
        const bool in0  = c0  < 10;   // rank < 10  <=>  in top-10 (jax stable ties)
        const bool in38 = c38 < 10;
        const bool in42 = c42 < 10;
        const bool has_nb = in0 || in38 || in42;

        // combo check: lane c (< 13) tests combo c (gathers are L1 hits)
        bool pass = false;
        if (lane < 13) {
            const int base3 = lane * 3;
            const float a0 = row[d_ccls[base3 + 0]];
            const float a1 = row[d_ccls[base3 + 1]];
            const float a2 = row[d_ccls[base3 + 2]];
            pass = (a0 >= d_clo[base3 + 0]) & (a0 <= d_chi[base3 + 0]) &
                   (a1 >= d_clo[base3 + 1]) & (a1 <= d_chi[base3 + 1]) &
                   (a2 >= d_clo[base3 + 2]) & (a2 <= d_chi[base3 + 2]);
        }
        const unsigned long long cm = __ballot(pass);
        const bool any   = (cm != 0ull);
        const int  first = any ? __builtin_ctzll(cm) : 0;

        const bool  bfj = any && !has_nb;
        const float bfs = bfj ? d_btab[first] : 0.0f;

        const bool  cpass = (v42 >= 0.1f) && (v42 <= 1.0f);
        const bool  cfj   = cpass || in42;
        const float cfs   = cpass ? 1.5f : (in42 ? 1.0f : 0.0f);

        if (lane == 0) {
            s_bfj[f] = (int)bfj;
            s_bfs[f] = bfs;
            s_cfj[f] = (int)cfj;
            s_cfs[f] = cfs;
        }
    }
    __syncthreads();

    // ---- stage 2: windowed group classification
    // wave 0: brux  (gsize=4, R=39, min_valid=2, required=2)
    // wave 1: cough (gsize=3, R=40, min_valid=2, required=2)
    if (wave < 2) {
        const int R = (wave == 0) ? 39 : 40;
        const int G = (wave == 0) ? 4 : 3;
        const int*   jarr = (wave == 0) ? s_bfj : s_cfj;
        const float* sarr = (wave == 0) ? s_bfs : s_cfs;

        bool  gj = false;
        float gs = -INFINITY;
        if (lane < R) {
            int   tc = 0;
            float ss = 0.0f;
            for (int k = 0; k < G; ++k) {  // scores are 0 where !judged, so plain sum
                tc += jarr[lane + k];
                ss += sarr[lane + k];
            }
            gj = (tc >= 2);
            gs = gj ? ss : -INFINITY;
        }
        const unsigned long long jm = __ballot(gj);
        const bool ok = __popcll(jm) >= 2;

        float m1 = gs;
#pragma unroll
        for (int s = 32; s > 0; s >>= 1) m1 = fmaxf(m1, __shfl_xor(m1, s));
        const unsigned long long em = __ballot(gs == m1);  // nonzero (-inf==-inf)
        const int amax = __builtin_ctzll(em);
        float gs2 = (lane == amax) ? -INFINITY : gs;
        float m2 = gs2;
#pragma unroll
        for (int s = 32; s > 0; s >>= 1) m2 = fmaxf(m2, __shfl_xor(m2, s));

        if (lane == 0) {
            const int jo = (wave == 0) ? 0 : 2 * NB;
            const int so = (wave == 0) ? NB : 3 * NB;
            out[jo + b] = ok ? 1.0f : 0.0f;
            out[so + b] = ok ? (m1 + m2) : 0.0f;
        }
    }
}

extern "C" void kernel_launch(void* const* d_in, const int* in_sizes, int n_in,
                              void* d_out, int out_size, void* d_ws, size_t ws_size,
                              hipStream_t stream) {
    const float* score = (const float*)d_in[0];
    float* out = (float*)d_out;
    sleep_cls_kernel<<<dim3(NB), dim3(256), 0, stream>>>(score, out);
}